// Round 6
// baseline (443.156 us; speedup 1.0000x reference)
//
#include <hip/hip_runtime.h>

#define HH 192
#define WW 192
#define LL (HH * WW)   // 36864
#define CC 512
#define KK 64
#define EPSF 1e-12f
typedef unsigned long long ull;

// k3 decomposition
#define NCHUNK 192
#define CHUNKL (LL / NCHUNK)   // 192
#define LT 32
#define CT 128

// ---------------------------------------------------------------- k0: wT[c][k] = conv_w[k][c]
__global__ __launch_bounds__(256) void k0_transpose(const float* __restrict__ w,
                                                    float* __restrict__ wT) {
    int idx = blockIdx.x * 256 + threadIdx.x;   // 32768 = KK*CC
    int k = idx >> 9;
    int c = idx & 511;
    wT[c * KK + k] = w[idx];
}

// ---------------------------------------------------------------- k1: 512 thr, lane=pixel, wave=(k-group-16, c-half)
// 8 waves: wid&3 -> k-group, wid>>2 -> c-half. LDS merge of partial acc.
__global__ __launch_bounds__(512) void k1_logits(const float* __restrict__ x,
                                                 const float* __restrict__ wT,
                                                 float* __restrict__ soft,
                                                 float* __restrict__ invn,
                                                 ull* __restrict__ keep) {
    __shared__ float accs[4][16][64];   // 16 KB: upper-half partials
    __shared__ float sss[64];
    __shared__ float sm1[4][64], sm2[4][64], ssum[4][64], sinv[64];
    __shared__ int   si1[4][64], si2[4][64];
    int t = threadIdx.x, lane = t & 63, wid = t >> 6;   // wid 0..7
    int l0 = blockIdx.x * 64;
    int kg = __builtin_amdgcn_readfirstlane((wid & 3) * 16);
    int ch = (wid >> 2) * 256;                           // c-half base

    const float* __restrict__ xcol = x + l0 + lane;

    float acc[16];
#pragma unroll
    for (int q = 0; q < 16; ++q) acc[q] = 0.f;
    float ss = 0.f;

    float xp[16], xn[16];
#pragma unroll
    for (int q = 0; q < 16; ++q) xp[q] = xcol[(size_t)(ch + q) * LL];

    for (int cb = ch; cb < ch + 256; cb += 16) {
        if (cb + 16 < ch + 256) {
#pragma unroll
            for (int q = 0; q < 16; ++q) xn[q] = xcol[(size_t)(cb + 16 + q) * LL];
        }
#pragma unroll
        for (int cc = 0; cc < 16; ++cc) {
            float xv = xp[cc];
            ss = fmaf(xv, xv, ss);                              // used by wid 0 & 4 only
            const float* wr = wT + (size_t)(cb + cc) * KK + kg; // uniform -> s_load
#pragma unroll
            for (int q = 0; q < 16; ++q) acc[q] = fmaf(wr[q], xv, acc[q]);
        }
        if (cb + 16 < ch + 256) {
#pragma unroll
            for (int q = 0; q < 16; ++q) xp[q] = xn[q];
        }
    }

    // merge c-halves: upper waves dump, lower waves add
    if (wid >= 4) {
        int w = wid - 4;
#pragma unroll
        for (int q = 0; q < 16; ++q) accs[w][q][lane] = acc[q];
        if (wid == 4) sss[lane] = ss;
    }
    __syncthreads();
    if (wid < 4) {
#pragma unroll
        for (int q = 0; q < 16; ++q) acc[q] += accs[wid][q][lane];
    }
    if (wid == 0) {
        ss += sss[lane];
        float iv = 1.0f / fmaxf(sqrtf(ss), EPSF);
        sinv[lane] = iv;
        invn[l0 + lane] = iv;
    }
    __syncthreads();
    float iv = sinv[lane];

    if (wid < 4) {
        float m1 = -3.0e38f, m2 = -3.0e38f; int i1 = 0, i2 = 0;
#pragma unroll
        for (int q = 0; q < 16; ++q) {
            float lg = acc[q] * iv;
            acc[q] = lg;
            if (lg > m1)      { m2 = m1; i2 = i1; m1 = lg; i1 = kg + q; }
            else if (lg > m2) { m2 = lg; i2 = kg + q; }
        }
        sm1[wid][lane] = m1; si1[wid][lane] = i1;
        sm2[wid][lane] = m2; si2[wid][lane] = i2;
    }
    __syncthreads();

    float M1 = -3.0e38f, M2 = -3.0e38f; int I1 = 0, I2 = 0;
    if (wid < 4) {
#pragma unroll
        for (int w2 = 0; w2 < 4; ++w2) {
            float a1 = sm1[w2][lane]; int b1 = si1[w2][lane];
            float a2 = sm2[w2][lane]; int b2 = si2[w2][lane];
            if (a1 > M1 || (a1 == M1 && b1 < I1)) { M2 = M1; I2 = I1; M1 = a1; I1 = b1; }
            else if (a1 > M2 || (a1 == M2 && b1 < I2)) { M2 = a1; I2 = b1; }
            if (a2 > M1 || (a2 == M1 && b2 < I1)) { M2 = M1; I2 = I1; M1 = a2; I1 = b2; }
            else if (a2 > M2 || (a2 == M2 && b2 < I2)) { M2 = a2; I2 = b2; }
        }
        float es = 0.f;
#pragma unroll
        for (int q = 0; q < 16; ++q) { float e = __expf(acc[q] - M1); acc[q] = e; es += e; }
        ssum[wid][lane] = es;
    }
    __syncthreads();
    if (wid < 4) {
        float St = ssum[0][lane] + ssum[1][lane] + ssum[2][lane] + ssum[3][lane];
        float rs = 1.0f / St;
        float4* sp = (float4*)(soft + (size_t)(l0 + lane) * KK + kg);
#pragma unroll
        for (int q4 = 0; q4 < 4; ++q4) {
            float4 v; v.x = acc[q4*4+0]*rs; v.y = acc[q4*4+1]*rs;
                      v.z = acc[q4*4+2]*rs; v.w = acc[q4*4+3]*rs;
            sp[q4] = v;
        }
        if (wid == 0) keep[l0 + lane] = (1ull << I1) | (1ull << I2);
    }
}

// ---------------------------------------------------------------- k2: w2[l][k] = soft*cnt*border^4*invn[l] (in place), S[k] += unscaled
// 8 pixels per wave -> grid 1152, 4.5 waves/SIMD
__global__ __launch_bounds__(256) void k2_weight(float* __restrict__ soft,
                                                 const ull* __restrict__ keep,
                                                 const float* __restrict__ invn,
                                                 float* __restrict__ S) {
    __shared__ float sred[4][64];
    int t = threadIdx.x, lane = t & 63, wid = t >> 6;
    int l0 = blockIdx.x * 32 + wid * 8;
    float sk = 0.f;
#pragma unroll
    for (int p = 0; p < 8; ++p) {
        int l = l0 + p;                           // wave-uniform
        int i = l / WW, j = l % WW;
        int m = min(min(i, HH - 1 - i), min(j, WW - 1 - j));
        float bm = (float)m; bm *= bm; bm *= bm;  // m^4
        int cnt = 0;
#pragma unroll
        for (int di = -1; di <= 1; ++di) {
            int ii = i + di;
            if (ii < 0 || ii >= HH) continue;
#pragma unroll
            for (int dj = -1; dj <= 1; ++dj) {
                int jj = j + dj;
                if (jj < 0 || jj >= WW) continue;
                ull nb = keep[ii * WW + jj];      // uniform -> s_load
                cnt += (int)((nb >> lane) & 1ull);
            }
        }
        float v = soft[(size_t)l * KK + lane];    // coalesced 256B
        float u = v * (float)cnt * bm;            // unscaled weight
        sk += u;
        soft[(size_t)l * KK + lane] = u * invn[l];
    }
    sred[wid][lane] = sk;
    __syncthreads();
    if (wid == 0)
        atomicAdd(&S[lane], sred[0][lane] + sred[1][lane] + sred[2][lane] + sred[3][lane]);
}

// ---------------------------------------------------------------- k3: partials[ch][k][c] = sum_{l in chunk} w2[l][k] * xn[c][l]
__global__ __launch_bounds__(256) void k3_gemm(const float* __restrict__ w2,
                                               const float* __restrict__ x,
                                               float* __restrict__ partials) {
    __shared__ float wt[LT][KK];
    __shared__ float xt[LT][CT + 4];
    int bx = blockIdx.x;
    int chunk = bx >> 2;                // 0..191
    int c0 = (bx & 3) * CT;
    int l0 = chunk * CHUNKL;
    int t = threadIdx.x;
    int tx = t & 15, ty = t >> 4;       // tx->c (8), ty->k (4)

    float acc[4][8];
#pragma unroll
    for (int r = 0; r < 4; ++r)
#pragma unroll
        for (int s = 0; s < 8; ++s) acc[r][s] = 0.f;

    for (int lb = 0; lb < CHUNKL; lb += LT) {
        {
            int kk = t & 63, r2 = t >> 6;        // r2 0..3
#pragma unroll
            for (int i = 0; i < 8; ++i)
                wt[r2 + 4 * i][kk] = w2[(size_t)(l0 + lb + r2 + 4 * i) * KK + kk];
        }
        {
            int lt = t & 31, cb = t >> 5;        // cb 0..7
            int gl = l0 + lb + lt;
#pragma unroll
            for (int j = 0; j < 16; ++j)
                xt[lt][cb + 8 * j] = x[(size_t)(c0 + cb + 8 * j) * LL + gl];
        }
        __syncthreads();
#pragma unroll 2
        for (int l2 = 0; l2 < LT; ++l2) {
            float4 wa = *(const float4*)&wt[l2][ty * 4];
            float4 xa = *(const float4*)&xt[l2][tx * 4];
            float4 xb = *(const float4*)&xt[l2][64 + tx * 4];
            float wk[4] = {wa.x, wa.y, wa.z, wa.w};
            float xs[8] = {xa.x, xa.y, xa.z, xa.w, xb.x, xb.y, xb.z, xb.w};
#pragma unroll
            for (int r = 0; r < 4; ++r)
#pragma unroll
                for (int s = 0; s < 8; ++s) acc[r][s] = fmaf(wk[r], xs[s], acc[r][s]);
        }
        __syncthreads();
    }
    float* pp = partials + (size_t)chunk * KK * CC;
#pragma unroll
    for (int r = 0; r < 4; ++r) {
        int k = ty * 4 + r;
        float4 va; va.x = acc[r][0]; va.y = acc[r][1]; va.z = acc[r][2]; va.w = acc[r][3];
        float4 vb; vb.x = acc[r][4]; vb.y = acc[r][5]; vb.z = acc[r][6]; vb.w = acc[r][7];
        *(float4*)&pp[(size_t)k * CC + c0 + tx * 4]      = va;
        *(float4*)&pp[(size_t)k * CC + c0 + 64 + tx * 4] = vb;
    }
}

// ---------------------------------------------------------------- k4a: reduce partials -> vlad, rowsq atomic
// grid (64, 4): block = (k, c-quarter of 128); 256 thr: tid&127 -> c, tid>>7 -> chunk half
__global__ __launch_bounds__(256) void k4a_reduce(const float* __restrict__ partials,
                                                  const float* __restrict__ S,
                                                  const float* __restrict__ cent,
                                                  float* __restrict__ vlad,
                                                  float* __restrict__ rowsq) {
    __shared__ float red[256];
    int k = blockIdx.x;
    int c = blockIdx.y * 128 + (threadIdx.x & 127);
    int half = threadIdx.x >> 7;                    // 0/1
    const float* pk = partials + (size_t)half * (NCHUNK / 2) * KK * CC + (size_t)k * CC + c;
    float s0 = 0.f, s1 = 0.f, s2 = 0.f, s3 = 0.f;
    for (int ch = 0; ch < NCHUNK / 2; ch += 4) {
        s0 += pk[(size_t)(ch + 0) * KK * CC];
        s1 += pk[(size_t)(ch + 1) * KK * CC];
        s2 += pk[(size_t)(ch + 2) * KK * CC];
        s3 += pk[(size_t)(ch + 3) * KK * CC];
    }
    red[threadIdx.x] = (s0 + s1) + (s2 + s3);
    __syncthreads();
    float vsq = 0.f;
    if (half == 0) {
        float v = red[threadIdx.x] + red[threadIdx.x + 128];
        v -= S[k] * cent[k * CC + c];
        vlad[k * CC + c] = v;
        vsq = v * v;
    }
    __syncthreads();
    red[threadIdx.x] = vsq;
    __syncthreads();
    for (int off = 64; off > 0; off >>= 1) {       // only tid<128 hold nonzero
        if (threadIdx.x < off) red[threadIdx.x] += red[threadIdx.x + off];
        __syncthreads();
    }
    if (threadIdx.x == 0) atomicAdd(&rowsq[k], red[0]);
}

// ---------------------------------------------------------------- k4g: rn[k] = row_scale * global_scale
__global__ __launch_bounds__(64) void k4g_scale(const float* __restrict__ rowsq,
                                                float* __restrict__ rn) {
    int lane = threadIdx.x;
    float tot = rowsq[lane];
    float r = 1.0f / fmaxf(sqrtf(tot), EPSF);
    float contrib = tot * r * r;
#pragma unroll
    for (int off = 32; off; off >>= 1) contrib += __shfl_xor(contrib, off, 64);
    float ginv = 1.0f / fmaxf(sqrtf(contrib), EPSF);
    rn[lane] = r * ginv;
}

// ---------------------------------------------------------------- k4c: out = vlad * rn[k]
__global__ __launch_bounds__(256) void k4c_finish(const float* __restrict__ vlad,
                                                  const float* __restrict__ rn,
                                                  float* __restrict__ out) {
    int idx4 = blockIdx.x * 256 + threadIdx.x;     // 8192 float4s
    int k = idx4 >> 7;                              // (idx4*4)>>9
    float s = rn[k];
    float4 v = ((const float4*)vlad)[idx4];
    v.x *= s; v.y *= s; v.z *= s; v.w *= s;
    ((float4*)out)[idx4] = v;
}

// ----------------------------------------------------------------
extern "C" void kernel_launch(void* const* d_in, const int* in_sizes, int n_in,
                              void* d_out, int out_size, void* d_ws, size_t ws_size,
                              hipStream_t stream) {
    const float* x      = (const float*)d_in[0];   // (512,192,192)
    const float* conv_w = (const float*)d_in[1];   // (64,512)
    const float* cent   = (const float*)d_in[2];   // (64,512)
    float* out = (float*)d_out;                    // 32768 fp32

    float* ws    = (float*)d_ws;
    float* wT    = ws;                              // 32768
    float* soft  = wT + 32768;                      // KK*LL (becomes w2 in place)
    float* invn  = soft + (size_t)KK * LL;          // 36864
    float* S     = invn + LL;                       // 64
    float* rowsq = S + KK;                          // 64
    float* rn    = rowsq + KK;                      // 64
    float* vlad  = rn + KK;                         // 32768
    ull*   keep  = (ull*)(vlad + 32768);            // LL u64 (offset multiple of 64 floats)
    float* partials = (float*)(keep + LL);          // NCHUNK*KK*CC floats (25.2 MB)

    hipMemsetAsync(S, 0, 2 * KK * sizeof(float), stream);   // S + rowsq

    k0_transpose<<<(KK * CC) / 256, 256, 0, stream>>>(conv_w, wT);
    k1_logits<<<LL / 64, 512, 0, stream>>>(x, wT, soft, invn, keep);
    k2_weight<<<LL / 32, 256, 0, stream>>>(soft, keep, invn, S);
    k3_gemm<<<NCHUNK * (CC / CT), 256, 0, stream>>>(soft, x, partials);
    k4a_reduce<<<dim3(KK, 4), 256, 0, stream>>>(partials, S, cent, vlad, rowsq);
    k4g_scale<<<1, 64, 0, stream>>>(rowsq, rn);
    k4c_finish<<<(KK * CC / 4) / 256, 256, 0, stream>>>(vlad, rn, out);
}

// Round 7
// 232.896 us; speedup vs baseline: 1.9028x; 1.9028x over previous
//
#include <hip/hip_runtime.h>

#define HH 192
#define WW 192
#define LL (HH * WW)   // 36864
#define CC 512
#define KK 64
#define EPSF 1e-12f
typedef unsigned long long ull;

// k3 decomposition
#define NCHUNK 192
#define CHUNKL (LL / NCHUNK)   // 192
#define LT 32
#define CT 128

// ---------------------------------------------------------------- k0: wT[c][k] = conv_w[k][c]
__global__ __launch_bounds__(256) void k0_transpose(const float* __restrict__ w,
                                                    float* __restrict__ wT) {
    int idx = blockIdx.x * 256 + threadIdx.x;   // 32768 = KK*CC
    int k = idx >> 9;
    int c = idx & 511;
    wT[c * KK + k] = w[idx];
}

// ---------------------------------------------------------------- k1: 512 thr, lane=pixel, wave=(k-group-16, c-half)
// 8 waves: wid&3 -> k-group, wid>>2 -> c-half. LDS merge of partial acc.
// CRITICAL: kg AND ch pinned with readfirstlane so wT rides s_load_dwordx16.
__global__ __launch_bounds__(512) void k1_logits(const float* __restrict__ x,
                                                 const float* __restrict__ wT,
                                                 float* __restrict__ soft,
                                                 float* __restrict__ invn,
                                                 ull* __restrict__ keep) {
    __shared__ float accs[4][16][64];   // 16 KB: upper-half partials
    __shared__ float sss[64];
    __shared__ float sm1[4][64], sm2[4][64], ssum[4][64], sinv[64];
    __shared__ int   si1[4][64], si2[4][64];
    int t = threadIdx.x, lane = t & 63, wid = t >> 6;   // wid 0..7
    int l0 = blockIdx.x * 64;
    int kg = __builtin_amdgcn_readfirstlane((wid & 3) * 16);
    int ch = __builtin_amdgcn_readfirstlane((wid >> 2) * 256);   // c-half base

    const float* __restrict__ xcol = x + l0 + lane;

    float acc[16];
#pragma unroll
    for (int q = 0; q < 16; ++q) acc[q] = 0.f;
    float ss = 0.f;

    float xp[16], xn[16];
#pragma unroll
    for (int q = 0; q < 16; ++q) xp[q] = xcol[(size_t)(ch + q) * LL];

    for (int cb = ch; cb < ch + 256; cb += 16) {
        if (cb + 16 < ch + 256) {
#pragma unroll
            for (int q = 0; q < 16; ++q) xn[q] = xcol[(size_t)(cb + 16 + q) * LL];
        }
#pragma unroll
        for (int cc = 0; cc < 16; ++cc) {
            float xv = xp[cc];
            ss = fmaf(xv, xv, ss);                              // consumed by wid 0/4 only
            const float* wr = wT + (size_t)(cb + cc) * KK + kg; // uniform -> s_load
#pragma unroll
            for (int q = 0; q < 16; ++q) acc[q] = fmaf(wr[q], xv, acc[q]);
        }
        if (cb + 16 < ch + 256) {
#pragma unroll
            for (int q = 0; q < 16; ++q) xp[q] = xn[q];
        }
    }

    // merge c-halves: upper waves dump, lower waves add
    if (wid >= 4) {
        int w = wid - 4;
#pragma unroll
        for (int q = 0; q < 16; ++q) accs[w][q][lane] = acc[q];
        if (wid == 4) sss[lane] = ss;
    }
    __syncthreads();
    if (wid < 4) {
#pragma unroll
        for (int q = 0; q < 16; ++q) acc[q] += accs[wid][q][lane];
    }
    if (wid == 0) {
        ss += sss[lane];
        float iv = 1.0f / fmaxf(sqrtf(ss), EPSF);
        sinv[lane] = iv;
        invn[l0 + lane] = iv;
    }
    __syncthreads();
    float iv = sinv[lane];

    if (wid < 4) {
        float m1 = -3.0e38f, m2 = -3.0e38f; int i1 = 0, i2 = 0;
#pragma unroll
        for (int q = 0; q < 16; ++q) {
            float lg = acc[q] * iv;
            acc[q] = lg;
            if (lg > m1)      { m2 = m1; i2 = i1; m1 = lg; i1 = kg + q; }
            else if (lg > m2) { m2 = lg; i2 = kg + q; }
        }
        sm1[wid][lane] = m1; si1[wid][lane] = i1;
        sm2[wid][lane] = m2; si2[wid][lane] = i2;
    }
    __syncthreads();

    float M1 = -3.0e38f, M2 = -3.0e38f; int I1 = 0, I2 = 0;
    if (wid < 4) {
#pragma unroll
        for (int w2 = 0; w2 < 4; ++w2) {
            float a1 = sm1[w2][lane]; int b1 = si1[w2][lane];
            float a2 = sm2[w2][lane]; int b2 = si2[w2][lane];
            if (a1 > M1 || (a1 == M1 && b1 < I1)) { M2 = M1; I2 = I1; M1 = a1; I1 = b1; }
            else if (a1 > M2 || (a1 == M2 && b1 < I2)) { M2 = a1; I2 = b1; }
            if (a2 > M1 || (a2 == M1 && b2 < I1)) { M2 = M1; I2 = I1; M1 = a2; I1 = b2; }
            else if (a2 > M2 || (a2 == M2 && b2 < I2)) { M2 = a2; I2 = b2; }
        }
        float es = 0.f;
#pragma unroll
        for (int q = 0; q < 16; ++q) { float e = __expf(acc[q] - M1); acc[q] = e; es += e; }
        ssum[wid][lane] = es;
    }
    __syncthreads();
    if (wid < 4) {
        float St = ssum[0][lane] + ssum[1][lane] + ssum[2][lane] + ssum[3][lane];
        float rs = 1.0f / St;
        float4* sp = (float4*)(soft + (size_t)(l0 + lane) * KK + kg);
#pragma unroll
        for (int q4 = 0; q4 < 4; ++q4) {
            float4 v; v.x = acc[q4*4+0]*rs; v.y = acc[q4*4+1]*rs;
                      v.z = acc[q4*4+2]*rs; v.w = acc[q4*4+3]*rs;
            sp[q4] = v;
        }
        if (wid == 0) keep[l0 + lane] = (1ull << I1) | (1ull << I2);
    }
}

// ---------------------------------------------------------------- k2: w2[l][k] = soft*cnt*border^4*invn[l] (in place), S[k] += unscaled
__global__ __launch_bounds__(256) void k2_weight(float* __restrict__ soft,
                                                 const ull* __restrict__ keep,
                                                 const float* __restrict__ invn,
                                                 float* __restrict__ S) {
    __shared__ float sred[4][64];
    int t = threadIdx.x, lane = t & 63, wid = t >> 6;
    int l0 = blockIdx.x * 32 + wid * 8;
    float sk = 0.f;
#pragma unroll
    for (int p = 0; p < 8; ++p) {
        int l = l0 + p;                           // wave-uniform
        int i = l / WW, j = l % WW;
        int m = min(min(i, HH - 1 - i), min(j, WW - 1 - j));
        float bm = (float)m; bm *= bm; bm *= bm;  // m^4
        int cnt = 0;
#pragma unroll
        for (int di = -1; di <= 1; ++di) {
            int ii = i + di;
            if (ii < 0 || ii >= HH) continue;
#pragma unroll
            for (int dj = -1; dj <= 1; ++dj) {
                int jj = j + dj;
                if (jj < 0 || jj >= WW) continue;
                ull nb = keep[ii * WW + jj];      // uniform -> s_load
                cnt += (int)((nb >> lane) & 1ull);
            }
        }
        float v = soft[(size_t)l * KK + lane];    // coalesced 256B
        float u = v * (float)cnt * bm;            // unscaled weight
        sk += u;
        soft[(size_t)l * KK + lane] = u * invn[l];
    }
    sred[wid][lane] = sk;
    __syncthreads();
    if (wid == 0)
        atomicAdd(&S[lane], sred[0][lane] + sred[1][lane] + sred[2][lane] + sred[3][lane]);
}

// ---------------------------------------------------------------- k3: partials[ch][k][c] = sum_{l in chunk} w2[l][k] * xn[c][l]
__global__ __launch_bounds__(256) void k3_gemm(const float* __restrict__ w2,
                                               const float* __restrict__ x,
                                               float* __restrict__ partials) {
    __shared__ float wt[LT][KK];
    __shared__ float xt[LT][CT + 4];
    int bx = blockIdx.x;
    int chunk = bx >> 2;                // 0..191
    int c0 = (bx & 3) * CT;
    int l0 = chunk * CHUNKL;
    int t = threadIdx.x;
    int tx = t & 15, ty = t >> 4;       // tx->c (8), ty->k (4)

    float acc[4][8];
#pragma unroll
    for (int r = 0; r < 4; ++r)
#pragma unroll
        for (int s = 0; s < 8; ++s) acc[r][s] = 0.f;

    for (int lb = 0; lb < CHUNKL; lb += LT) {
        {
            int kk = t & 63, r2 = t >> 6;        // r2 0..3
#pragma unroll
            for (int i = 0; i < 8; ++i)
                wt[r2 + 4 * i][kk] = w2[(size_t)(l0 + lb + r2 + 4 * i) * KK + kk];
        }
        {
            int lt = t & 31, cb = t >> 5;        // cb 0..7
            int gl = l0 + lb + lt;
#pragma unroll
            for (int j = 0; j < 16; ++j)
                xt[lt][cb + 8 * j] = x[(size_t)(c0 + cb + 8 * j) * LL + gl];
        }
        __syncthreads();
#pragma unroll 2
        for (int l2 = 0; l2 < LT; ++l2) {
            float4 wa = *(const float4*)&wt[l2][ty * 4];
            float4 xa = *(const float4*)&xt[l2][tx * 4];
            float4 xb = *(const float4*)&xt[l2][64 + tx * 4];
            float wk[4] = {wa.x, wa.y, wa.z, wa.w};
            float xs[8] = {xa.x, xa.y, xa.z, xa.w, xb.x, xb.y, xb.z, xb.w};
#pragma unroll
            for (int r = 0; r < 4; ++r)
#pragma unroll
                for (int s = 0; s < 8; ++s) acc[r][s] = fmaf(wk[r], xs[s], acc[r][s]);
        }
        __syncthreads();
    }
    float* pp = partials + (size_t)chunk * KK * CC;
#pragma unroll
    for (int r = 0; r < 4; ++r) {
        int k = ty * 4 + r;
        float4 va; va.x = acc[r][0]; va.y = acc[r][1]; va.z = acc[r][2]; va.w = acc[r][3];
        float4 vb; vb.x = acc[r][4]; vb.y = acc[r][5]; vb.z = acc[r][6]; vb.w = acc[r][7];
        *(float4*)&pp[(size_t)k * CC + c0 + tx * 4]      = va;
        *(float4*)&pp[(size_t)k * CC + c0 + 64 + tx * 4] = vb;
    }
}

// ---------------------------------------------------------------- k4a: reduce partials -> vlad, rowsq atomic
__global__ __launch_bounds__(256) void k4a_reduce(const float* __restrict__ partials,
                                                  const float* __restrict__ S,
                                                  const float* __restrict__ cent,
                                                  float* __restrict__ vlad,
                                                  float* __restrict__ rowsq) {
    __shared__ float red[256];
    int k = blockIdx.x;
    int c = blockIdx.y * 128 + (threadIdx.x & 127);
    int half = threadIdx.x >> 7;                    // 0/1
    const float* pk = partials + (size_t)half * (NCHUNK / 2) * KK * CC + (size_t)k * CC + c;
    float s0 = 0.f, s1 = 0.f, s2 = 0.f, s3 = 0.f;
    for (int ch = 0; ch < NCHUNK / 2; ch += 4) {
        s0 += pk[(size_t)(ch + 0) * KK * CC];
        s1 += pk[(size_t)(ch + 1) * KK * CC];
        s2 += pk[(size_t)(ch + 2) * KK * CC];
        s3 += pk[(size_t)(ch + 3) * KK * CC];
    }
    red[threadIdx.x] = (s0 + s1) + (s2 + s3);
    __syncthreads();
    float vsq = 0.f;
    if (half == 0) {
        float v = red[threadIdx.x] + red[threadIdx.x + 128];
        v -= S[k] * cent[k * CC + c];
        vlad[k * CC + c] = v;
        vsq = v * v;
    }
    __syncthreads();
    red[threadIdx.x] = vsq;
    __syncthreads();
    for (int off = 64; off > 0; off >>= 1) {       // only tid<128 hold nonzero
        if (threadIdx.x < off) red[threadIdx.x] += red[threadIdx.x + off];
        __syncthreads();
    }
    if (threadIdx.x == 0) atomicAdd(&rowsq[k], red[0]);
}

// ---------------------------------------------------------------- k4g: rn[k] = row_scale * global_scale
__global__ __launch_bounds__(64) void k4g_scale(const float* __restrict__ rowsq,
                                                float* __restrict__ rn) {
    int lane = threadIdx.x;
    float tot = rowsq[lane];
    float r = 1.0f / fmaxf(sqrtf(tot), EPSF);
    float contrib = tot * r * r;
#pragma unroll
    for (int off = 32; off; off >>= 1) contrib += __shfl_xor(contrib, off, 64);
    float ginv = 1.0f / fmaxf(sqrtf(contrib), EPSF);
    rn[lane] = r * ginv;
}

// ---------------------------------------------------------------- k4c: out = vlad * rn[k]
__global__ __launch_bounds__(256) void k4c_finish(const float* __restrict__ vlad,
                                                  const float* __restrict__ rn,
                                                  float* __restrict__ out) {
    int idx4 = blockIdx.x * 256 + threadIdx.x;     // 8192 float4s
    int k = idx4 >> 7;
    float s = rn[k];
    float4 v = ((const float4*)vlad)[idx4];
    v.x *= s; v.y *= s; v.z *= s; v.w *= s;
    ((float4*)out)[idx4] = v;
}

// ----------------------------------------------------------------
extern "C" void kernel_launch(void* const* d_in, const int* in_sizes, int n_in,
                              void* d_out, int out_size, void* d_ws, size_t ws_size,
                              hipStream_t stream) {
    const float* x      = (const float*)d_in[0];   // (512,192,192)
    const float* conv_w = (const float*)d_in[1];   // (64,512)
    const float* cent   = (const float*)d_in[2];   // (64,512)
    float* out = (float*)d_out;                    // 32768 fp32

    float* ws    = (float*)d_ws;
    float* wT    = ws;                              // 32768
    float* soft  = wT + 32768;                      // KK*LL (becomes w2 in place)
    float* invn  = soft + (size_t)KK * LL;          // 36864
    float* S     = invn + LL;                       // 64
    float* rowsq = S + KK;                          // 64
    float* rn    = rowsq + KK;                      // 64
    float* vlad  = rn + KK;                         // 32768
    ull*   keep  = (ull*)(vlad + 32768);            // LL u64
    float* partials = (float*)(keep + LL);          // NCHUNK*KK*CC floats (25.2 MB)

    hipMemsetAsync(S, 0, 2 * KK * sizeof(float), stream);   // S + rowsq

    k0_transpose<<<(KK * CC) / 256, 256, 0, stream>>>(conv_w, wT);
    k1_logits<<<LL / 64, 512, 0, stream>>>(x, wT, soft, invn, keep);
    k2_weight<<<LL / 32, 256, 0, stream>>>(soft, keep, invn, S);
    k3_gemm<<<NCHUNK * (CC / CT), 256, 0, stream>>>(soft, x, partials);
    k4a_reduce<<<dim3(KK, 4), 256, 0, stream>>>(partials, S, cent, vlad, rowsq);
    k4g_scale<<<1, 64, 0, stream>>>(rowsq, rn);
    k4c_finish<<<(KK * CC / 4) / 256, 256, 0, stream>>>(vlad, rn, out);
}